// Round 4
// baseline (793.252 us; speedup 1.0000x reference)
//
#include <hip/hip_runtime.h>
#include <cstdint>
#include <cstddef>

namespace {

constexpr int kH  = 1024;
constexpr int kB  = 64;
constexpr int kN  = 32;
constexpr int kT  = 400;
constexpr int kV  = 32000;
constexpr int kM  = kN * kB;   // 2048
constexpr int k3H = 3 * kH;    // 3072

typedef _Float16 f16;
typedef _Float16 f16x4 __attribute__((ext_vector_type(4)));
typedef _Float16 f16x8 __attribute__((ext_vector_type(8)));
typedef float    f32x4v __attribute__((ext_vector_type(4)));

__device__ __forceinline__ void gload_lds16(const void* g, void* l) {
  __builtin_amdgcn_global_load_lds((__attribute__((address_space(1))) void*)g,
                                   (__attribute__((address_space(3))) void*)l,
                                   16, 0, 0);
}

__device__ __forceinline__ uint32_t pack_f16x2(f16 lo, f16 hi) {
  union { f16 h[2]; uint32_t u; } c;
  c.h[0] = lo; c.h[1] = hi;
  return c.u;
}

// ---------------- elementwise helpers ----------------

__global__ void cvt_f16_kernel(const float* __restrict__ src, f16* __restrict__ dst, int n4) {
  int i = blockIdx.x * blockDim.x + threadIdx.x;
  const int stride = gridDim.x * blockDim.x;
  for (; i < n4; i += stride) {
    float4 v = reinterpret_cast<const float4*>(src)[i];
    f16x4 o = { (f16)v.x, (f16)v.y, (f16)v.z, (f16)v.w };
    reinterpret_cast<f16x4*>(dst)[i] = o;
  }
}

__global__ void gather_x_kernel(const int* __restrict__ seq, const float* __restrict__ emb,
                                f16* __restrict__ xh) {
  const int m = blockIdx.x;               // 0..2047 = n*64+b
  const int tok = seq[m];
  float4 v = reinterpret_cast<const float4*>(emb + (size_t)tok * kH)[threadIdx.x];
  f16x4 o = { (f16)v.x, (f16)v.y, (f16)v.z, (f16)v.w };
  reinterpret_cast<f16x4*>(xh + (size_t)m * kH)[threadIdx.x] = o;
}

__global__ void init_h_kernel(const float* __restrict__ lh, f16* __restrict__ hh0) {
  const int i = blockIdx.x * blockDim.x + threadIdx.x;   // 16384 float4s
  float4 v = reinterpret_cast<const float4*>(lh)[i];
  f16x4 o = { (f16)v.x, (f16)v.y, (f16)v.z, (f16)v.w };
  reinterpret_cast<f16x4*>(hh0)[i] = o;
}

// ---------------- main GEMM: C = A * Bt^T (+bias)(+tanh) ----------------
// A: [M][K] f16, Bt: [N][K] f16 (weights are (out,in) row-major = ready-transposed)
// 128x128 tile, BK=64, 4 waves, wave = 64x64 via 4x4 mfma_f32_16x16x32_f16.

template <bool TANH, typename OUT_T>
__global__ __launch_bounds__(256)
void gemm_bt_kernel(const f16* __restrict__ A, const f16* __restrict__ Bt,
                    const float* __restrict__ bias, OUT_T* __restrict__ C,
                    int M, int N, int K) {
  __shared__ __align__(16) f16 As[128 * 64];
  __shared__ __align__(16) f16 Bs[128 * 64];
  const int tid  = threadIdx.x;
  const int wave = tid >> 6;
  const int lane = tid & 63;
  const int m0 = blockIdx.x * 128;
  const int n0 = blockIdx.y * 128;
  const int wm = (wave >> 1) * 64;
  const int wn = (wave & 1) * 64;
  const int rsub = lane >> 3;          // staging: row within 8-row chunk
  const int coff = (lane & 7) * 8;     // staging: f16 col offset (16B per lane)
  f32x4v acc[4][4] = {};
  const int nk = K >> 6;
  for (int kc = 0; kc < nk; ++kc) {
    const f16* Ag = A + (size_t)m0 * K + kc * 64;
    const f16* Bg = Bt + (size_t)n0 * K + kc * 64;
    for (int c = wave; c < 16; c += 4) {        // 16 chunks of 1KB each for A and B
      const int row = c * 8 + rsub;
      gload_lds16(Ag + (size_t)row * K + coff, &As[c * 512]);
      gload_lds16(Bg + (size_t)row * K + coff, &Bs[c * 512]);
    }
    __syncthreads();
    #pragma unroll
    for (int kk = 0; kk < 2; ++kk) {
      const int ko = kk * 32 + (lane >> 4) * 8;
      f16x8 af[4], bfr[4];
      #pragma unroll
      for (int i = 0; i < 4; ++i) {
        af[i]  = *reinterpret_cast<const f16x8*>(&As[(wm + i * 16 + (lane & 15)) * 64 + ko]);
        bfr[i] = *reinterpret_cast<const f16x8*>(&Bs[(wn + i * 16 + (lane & 15)) * 64 + ko]);
      }
      #pragma unroll
      for (int mi = 0; mi < 4; ++mi)
        #pragma unroll
        for (int ni = 0; ni < 4; ++ni)
          acc[mi][ni] = __builtin_amdgcn_mfma_f32_16x16x32_f16(af[mi], bfr[ni], acc[mi][ni], 0, 0, 0);
    }
    __syncthreads();
  }
  // epilogue: D row = (lane>>4)*4+r, col = lane&15
  const int rb = (lane >> 4) * 4;
  const int cb = lane & 15;
  #pragma unroll
  for (int mi = 0; mi < 4; ++mi) {
    #pragma unroll
    for (int ni = 0; ni < 4; ++ni) {
      const int col = n0 + wn + ni * 16 + cb;
      const float bv = bias[col];
      #pragma unroll
      for (int r = 0; r < 4; ++r) {
        const int row = m0 + wm + mi * 16 + rb + r;
        float v = acc[mi][ni][r] + bv;
        if (TANH) v = tanhf(v);
        C[(size_t)row * N + col] = (OUT_T)v;
      }
    }
  }
}

// ---------------- persistent GRU ----------------
// 64 blocks x 256 threads, 1 block/CU. Block owns output cols j0..j0+15.
// W_hh fragments persistent in registers (wave w owns K-slice w*256).
// Own-column h kept in f32 registers across steps (hreg).
// Cross-block h exchange: packed-f16 relaxed agent stores (sc1 write-through).
// Sync: DISTRIBUTED per-block epoch flags. Producer: h stores -> syncthreads
// (drains vmcnt -> stores at coherence point) -> tid0 stores flag[block]=step+1
// (plain relaxed store, no RMW). Consumer: wave w needs only its K-slice's 16
// producer blocks; lanes poll flag[w*16+(lane&15)] with relaxed loads until
// __all(>=step), then ONE acquire fence (buffer_inv) before the h loads.
// Monotone flags + acyclic step deps => deadlock-free.

__global__ __launch_bounds__(256, 1)
void gru_persist_kernel(const f16* __restrict__ Whh, const float* __restrict__ bhh,
                        const float* __restrict__ gi, const float* __restrict__ lh,
                        f16* __restrict__ HHa, f16* __restrict__ HHb,
                        f16* __restrict__ cath, float* __restrict__ hiddenOut,
                        unsigned int* __restrict__ flags) {
  __shared__ float ghp[4][64][49];     // [wave][m][48 cols, padded] partials
  const int tid  = threadIdx.x;
  const int wave = tid >> 6;
  const int lane = tid & 63;
  const int ln   = lane & 15;
  const int khi  = lane >> 4;
  const int j0   = blockIdx.x * 16;
  const int kw   = wave * 256;         // this wave's K-slice
  const int q    = tid & 7;            // fusion: col pair index
  const int mB   = tid >> 3;           // fusion: row base (0..31)
  const int myprod = wave * 16 + ln;   // producer block this lane polls

  // B fragments: persistent in registers across all steps (96 VGPR)
  f16x8 bfr[3][8];
  #pragma unroll
  for (int s = 0; s < 3; ++s)
    #pragma unroll
    for (int ks = 0; ks < 8; ++ks)
      bfr[s][ks] = *reinterpret_cast<const f16x8*>(
          &Whh[(size_t)(s * kH + j0 + ln) * kH + kw + ks * 32 + khi * 8]);

  // own-column h in f32 registers; biases preloaded
  float hreg[2][2];
  float bR[2], bZ[2], bN[2];
  #pragma unroll
  for (int e = 0; e < 2; ++e) {
    const int j = j0 + 2 * q + e;
    hreg[0][e] = lh[(size_t)mB * kH + j];
    hreg[1][e] = lh[(size_t)(mB + 32) * kH + j];
    bR[e] = bhh[j];
    bZ[e] = bhh[kH + j];
    bN[e] = bhh[2 * kH + j];
  }

  for (int step = 0; step < kN; ++step) {
    const f16* hh  = (step & 1) ? HHb : HHa;
    f16*       hho = (step & 1) ? HHa : HHb;

    // gi prefetch for this step (no h dependence; flies during the poll)
    float2 giL[2][3];
    #pragma unroll
    for (int hm = 0; hm < 2; ++hm) {
      const size_t mm = (size_t)step * kB + mB + hm * 32;
      #pragma unroll
      for (int s = 0; s < 3; ++s)
        giL[hm][s] = *reinterpret_cast<const float2*>(&gi[mm * k3H + s * kH + j0 + 2 * q]);
    }

    if (step > 0) {
      // wait only for this wave's 16 K-slice producers
      while (true) {
        unsigned int f = __hip_atomic_load(&flags[myprod], __ATOMIC_RELAXED,
                                           __HIP_MEMORY_SCOPE_AGENT);
        if (__all(f >= (unsigned int)step)) break;
        __builtin_amdgcn_s_sleep(1);
      }
      __builtin_amdgcn_fence(__ATOMIC_ACQUIRE, "agent");  // one inv; fresh h reads
    }

    // A fragments: direct global->reg, all 32 loads in flight at once
    f16x8 af[8][4];
    #pragma unroll
    for (int ks = 0; ks < 8; ++ks)
      #pragma unroll
      for (int mi = 0; mi < 4; ++mi)
        af[ks][mi] = *reinterpret_cast<const f16x8*>(
            &hh[(size_t)(mi * 16 + ln) * kH + kw + ks * 32 + khi * 8]);

    f32x4v acc[4][3] = {};
    #pragma unroll
    for (int ks = 0; ks < 8; ++ks)
      #pragma unroll
      for (int mi = 0; mi < 4; ++mi)
        #pragma unroll
        for (int s = 0; s < 3; ++s)
          acc[mi][s] = __builtin_amdgcn_mfma_f32_16x16x32_f16(af[ks][mi], bfr[s][ks], acc[mi][s], 0, 0, 0);

    // K-split partials -> LDS (padded pitch 49: conflict-free)
    #pragma unroll
    for (int mi = 0; mi < 4; ++mi)
      #pragma unroll
      for (int s = 0; s < 3; ++s)
        #pragma unroll
        for (int r = 0; r < 4; ++r)
          ghp[wave][mi * 16 + khi * 4 + r][s * 16 + ln] = acc[mi][s][r];
    __syncthreads();

    // gate fusion: each thread owns rows {mB, mB+32} x cols {2q, 2q+1}
    #pragma unroll
    for (int hm = 0; hm < 2; ++hm) {
      const int m = mB + hm * 32;
      const size_t mm = (size_t)step * kB + m;
      float hv[2];
      #pragma unroll
      for (int e = 0; e < 2; ++e) {
        const int jj = 2 * q + e;
        const float gr = ghp[0][m][jj]      + ghp[1][m][jj]      + ghp[2][m][jj]      + ghp[3][m][jj]      + bR[e];
        const float gz = ghp[0][m][16 + jj] + ghp[1][m][16 + jj] + ghp[2][m][16 + jj] + ghp[3][m][16 + jj] + bZ[e];
        const float gn = ghp[0][m][32 + jj] + ghp[1][m][32 + jj] + ghp[2][m][32 + jj] + ghp[3][m][32 + jj] + bN[e];
        const float ir  = (e ? giL[hm][0].y : giL[hm][0].x);
        const float iz  = (e ? giL[hm][1].y : giL[hm][1].x);
        const float inn = (e ? giL[hm][2].y : giL[hm][2].x);
        const float r  = 1.0f / (1.0f + expf(-(ir + gr)));
        const float z  = 1.0f / (1.0f + expf(-(iz + gz)));
        const float nn = tanhf(inn + r * gn);
        hv[e] = (1.0f - z) * nn + z * hreg[hm][e];
        hreg[hm][e] = hv[e];
      }
      const uint32_t pk = pack_f16x2((f16)hv[0], (f16)hv[1]);
      // cross-block exchange: write-through to coherence point (sc1), no wbl2
      __hip_atomic_store((uint32_t*)&hho[(size_t)m * kH + j0 + 2 * q], pk,
                         __ATOMIC_RELAXED, __HIP_MEMORY_SCOPE_AGENT);
      *reinterpret_cast<uint32_t*>(&cath[mm * (size_t)k3H + j0 + 2 * q]) = pk;
      if (step == kN - 1) {
        float2 hv2 = { hv[0], hv[1] };
        *reinterpret_cast<float2*>(&hiddenOut[(size_t)m * kH + j0 + 2 * q]) = hv2;
      }
    }

    if (step < kN - 1) {
      // drains every thread's vmcnt (compiler emits s_waitcnt vmcnt(0) before
      // s_barrier) -> all h stores are at the coherence point; also guards ghp.
      __syncthreads();
      if (tid == 0)
        __hip_atomic_store(&flags[blockIdx.x], (unsigned int)(step + 1),
                           __ATOMIC_RELAXED, __HIP_MEMORY_SCOPE_AGENT);
    }
  }
}

// ---------------- attention (softmax over t is independent of n) ----------------

__global__ void attn_prep_kernel(const float* __restrict__ attn_W, const float* __restrict__ attn_b,
                                 const float* __restrict__ v, float* __restrict__ u2,
                                 float* __restrict__ biasS) {
  const int h = blockIdx.x;        // 0..1023 -> u2[h]; 1024 -> bias scalar
  const int lane = threadIdx.x;    // 64
  float sum = 0.0f;
  if (h < kH) {
    for (int k = lane; k < kH; k += 64)
      sum += attn_W[(size_t)k * (2 * kH) + kH + h] * v[k];
  } else {
    for (int k = lane; k < kH; k += 64)
      sum += attn_b[k] * v[k];
  }
  #pragma unroll
  for (int o = 32; o > 0; o >>= 1) sum += __shfl_xor(sum, o);
  if (lane == 0) {
    if (h < kH) u2[h] = sum; else biasS[0] = sum;
  }
}

__global__ void attn_scores_kernel(const float* __restrict__ enc0, const float* __restrict__ enc1,
                                   const float* __restrict__ u2, const float* __restrict__ biasS,
                                   float* __restrict__ c) {
  const int wid  = blockIdx.x * 4 + (threadIdx.x >> 6);  // one wave per (e,t,b)
  const int lane = threadIdx.x & 63;
  const int e   = wid / (kT * kB);
  const int rem = wid % (kT * kB);
  const int t = rem / kB;
  const int b = rem % kB;
  const float* row = (e ? enc1 : enc0) + ((size_t)t * kB + b) * kH;
  float sum = 0.0f;
  #pragma unroll
  for (int i = 0; i < 4; ++i) {
    float4 ev = *reinterpret_cast<const float4*>(&row[i * 256 + lane * 4]);
    float4 uv = *reinterpret_cast<const float4*>(&u2[i * 256 + lane * 4]);
    sum += ev.x * uv.x + ev.y * uv.y + ev.z * uv.z + ev.w * uv.w;
  }
  #pragma unroll
  for (int o = 32; o > 0; o >>= 1) sum += __shfl_xor(sum, o);
  if (lane == 0) c[((size_t)e * kB + b) * kT + t] = sum + biasS[0];
}

__global__ void attn_softmax_kernel(const float* __restrict__ c, float* __restrict__ wsm,
                                    float* __restrict__ uw, float* __restrict__ bw) {
  const int eb = blockIdx.x;       // 0..127
  const int e = eb >> 6, b = eb & 63;
  __shared__ float row[kT];
  __shared__ float red[8];
  const float* cr = c + (size_t)eb * kT;
  const int tid = threadIdx.x;     // 256
  float lmax = -1e30f;
  for (int t = tid; t < kT; t += 256) { float v = cr[t]; row[t] = v; lmax = fmaxf(lmax, v); }
  #pragma unroll
  for (int o = 32; o > 0; o >>= 1) lmax = fmaxf(lmax, __shfl_xor(lmax, o));
  if ((tid & 63) == 0) red[tid >> 6] = lmax;
  __syncthreads();
  const float m = fmaxf(fmaxf(red[0], red[1]), fmaxf(red[2], red[3]));
  float lsum = 0.0f;
  for (int t = tid; t < kT; t += 256) { float ev = expf(row[t] - m); row[t] = ev; lsum += ev; }
  #pragma unroll
  for (int o = 32; o > 0; o >>= 1) lsum += __shfl_xor(lsum, o);
  if ((tid & 63) == 0) red[4 + (tid >> 6)] = lsum;
  __syncthreads();
  const float inv = 1.0f / (red[4] + red[5] + red[6] + red[7]);
  for (int t = tid; t < kT; t += 256) row[t] *= inv;
  __syncthreads();
  float* wrow = wsm + (size_t)eb * kT;
  for (int t = tid; t < kT; t += 256) wrow[t] = row[t];
  float* outp = (e ? bw : uw) + (size_t)b * kN * kT;   // w is identical for every n
  for (int i = tid; i < kN * kT; i += 256) outp[i] = row[i % kT];
}

__global__ void attn_ctx_kernel(const float* __restrict__ enc0, const float* __restrict__ enc1,
                                const float* __restrict__ wsm, f16* __restrict__ cath) {
  const int bid = blockIdx.x;          // e(2) x b(64) x hc(4)
  const int hc = bid & 3;
  const int b  = (bid >> 2) & 63;
  const int e  = bid >> 8;
  const float* enc = e ? enc1 : enc0;
  __shared__ float w[kT];
  const int tid = threadIdx.x;         // 256
  const float* wrow = wsm + ((size_t)e * kB + b) * kT;
  for (int t = tid; t < kT; t += 256) w[t] = wrow[t];
  __syncthreads();
  const int hcol = hc * 256 + tid;
  float acc = 0.0f;
  #pragma unroll 4
  for (int t = 0; t < kT; ++t)
    acc += w[t] * enc[((size_t)t * kB + b) * kH + hcol];
  const f16 v = (f16)acc;
  #pragma unroll
  for (int n = 0; n < kN; ++n)         // ctx is independent of n -> replicate
    cath[((size_t)(n * kB + b)) * k3H + kH + e * kH + hcol] = v;
}

}  // namespace

// ---------------- launch ----------------

extern "C" void kernel_launch(void* const* d_in, const int* in_sizes, int n_in,
                              void* d_out, int out_size, void* d_ws, size_t ws_size,
                              hipStream_t stream) {
  (void)in_sizes; (void)n_in; (void)out_size; (void)ws_size;
  const int*   seq    = (const int*)d_in[0];
  const float* lh     = (const float*)d_in[1];
  const float* enc0   = (const float*)d_in[2];
  const float* enc1   = (const float*)d_in[3];
  const float* emb    = (const float*)d_in[4];
  const float* W_ih   = (const float*)d_in[5];
  const float* W_hh   = (const float*)d_in[6];
  const float* b_ih   = (const float*)d_in[7];
  const float* b_hh   = (const float*)d_in[8];
  const float* attn_W = (const float*)d_in[9];
  const float* attn_b = (const float*)d_in[10];
  const float* attn_v = (const float*)d_in[11];
  const float* cW     = (const float*)d_in[12];
  const float* cb     = (const float*)d_in[13];
  const float* oW     = (const float*)d_in[14];
  const float* ob     = (const float*)d_in[15];
  float* out = (float*)d_out;

  // workspace layout (all 256B-aligned by construction)
  char* ws = (char*)d_ws;
  constexpr size_t oWih = 0;                         // 3072x1024 f16
  constexpr size_t oWhh = oWih + 6291456;
  constexpr size_t oCW  = oWhh + 6291456;
  constexpr size_t oOW  = oCW + 6291456;             // 32000x1024 f16
  constexpr size_t oX   = oOW + 65536000;            // 2048x1024 f16
  constexpr size_t oGI  = oX + 4194304;              // 2048x3072 f32
  constexpr size_t oH0  = oGI + 25165824;            // (unused, kept for layout stability)
  constexpr size_t oH1  = oH0 + 262144;
  constexpr size_t oHH0 = oH1 + 262144;              // 64x1024 f16
  constexpr size_t oHH1 = oHH0 + 131072;
  constexpr size_t oCAT = oHH1 + 131072;             // 2048x3072 f16
  constexpr size_t oH2  = oCAT + 12582912;           // 2048x1024 f16
  constexpr size_t oU2  = oH2 + 4194304;             // 1024 f32
  constexpr size_t oBS  = oU2 + 4096;                // 1 f32
  constexpr size_t oC   = oBS + 256;                 // 2x64x400 f32
  constexpr size_t oWSM = oC + 204800;               // 2x64x400 f32
  constexpr size_t oCTR = oWSM + 204800;             // 64 u32 epoch flags

  f16*   Wih_h = (f16*)(ws + oWih);
  f16*   Whh_h = (f16*)(ws + oWhh);
  f16*   cW_h  = (f16*)(ws + oCW);
  f16*   oW_h  = (f16*)(ws + oOW);
  f16*   X_h   = (f16*)(ws + oX);
  float* GI    = (float*)(ws + oGI);
  f16*   HH0   = (f16*)(ws + oHH0);
  f16*   HH1   = (f16*)(ws + oHH1);
  f16*   CAT   = (f16*)(ws + oCAT);
  f16*   H2    = (f16*)(ws + oH2);
  float* U2    = (float*)(ws + oU2);
  float* BS    = (float*)(ws + oBS);
  float* Cb    = (float*)(ws + oC);
  float* WSM   = (float*)(ws + oWSM);
  unsigned int* FLAGS = (unsigned int*)(ws + oCTR);

  constexpr size_t oHidden = (size_t)kM * kV;        // 65,536,000
  constexpr size_t oUW = oHidden + (size_t)kB * kH;  // 65,601,536
  constexpr size_t oBW = oUW + (size_t)kB * kN * kT; // 66,420,736

  // weight converts f32 -> f16
  cvt_f16_kernel<<<1024, 256, 0, stream>>>(W_ih, Wih_h, k3H * kH / 4);
  cvt_f16_kernel<<<1024, 256, 0, stream>>>(W_hh, Whh_h, k3H * kH / 4);
  cvt_f16_kernel<<<1024, 256, 0, stream>>>(cW,   cW_h,  kH * k3H / 4);
  cvt_f16_kernel<<<2048, 256, 0, stream>>>(oW,   oW_h,  kV * kH / 4);
  gather_x_kernel<<<kM, 256, 0, stream>>>(seq, emb, X_h);
  init_h_kernel<<<64, 256, 0, stream>>>(lh, HH0);
  hipMemsetAsync(FLAGS, 0, 64 * sizeof(unsigned int), stream);

  // gi = x @ W_ih^T + b_ih  (batched over all steps)
  gemm_bt_kernel<false, float><<<dim3(16, 24), 256, 0, stream>>>(X_h, Wih_h, b_ih, GI, kM, k3H, kH);

  // GRU recurrence: one persistent kernel, distributed-flag barrier per step
  gru_persist_kernel<<<64, 256, 0, stream>>>(Whh_h, b_hh, GI, lh, HH0, HH1, CAT,
                                             out + oHidden, FLAGS);

  // attention (n-independent): scores -> softmax (writes uw/bw replicated) -> ctx
  attn_prep_kernel<<<1025, 64, 0, stream>>>(attn_W, attn_b, attn_v, U2, BS);
  attn_scores_kernel<<<2 * kT * kB / 4, 256, 0, stream>>>(enc0, enc1, U2, BS, Cb);
  attn_softmax_kernel<<<128, 256, 0, stream>>>(Cb, WSM, out + oUW, out + oBW);
  attn_ctx_kernel<<<512, 256, 0, stream>>>(enc0, enc1, WSM, CAT);

  // h = tanh(cat @ concat_W^T + concat_b)   (f16 out for final GEMM)
  gemm_bt_kernel<true, f16><<<dim3(16, 8), 256, 0, stream>>>(CAT, cW_h, cb, H2, kM, kH, k3H);
  // output = h @ out_W^T + out_b
  gemm_bt_kernel<false, float><<<dim3(16, 250), 256, 0, stream>>>(H2, oW_h, ob, out, kM, kV, kH);
}

// Round 5
// 691.381 us; speedup vs baseline: 1.1473x; 1.1473x over previous
//
#include <hip/hip_runtime.h>
#include <cstdint>
#include <cstddef>

namespace {

constexpr int kH  = 1024;
constexpr int kB  = 64;
constexpr int kN  = 32;
constexpr int kT  = 400;
constexpr int kV  = 32000;
constexpr int kM  = kN * kB;   // 2048
constexpr int k3H = 3 * kH;    // 3072

typedef _Float16 f16;
typedef _Float16 f16x4 __attribute__((ext_vector_type(4)));
typedef _Float16 f16x8 __attribute__((ext_vector_type(8)));
typedef float    f32x4v __attribute__((ext_vector_type(4)));

__device__ __forceinline__ void gload_lds16(const void* g, void* l) {
  __builtin_amdgcn_global_load_lds((__attribute__((address_space(1))) void*)g,
                                   (__attribute__((address_space(3))) void*)l,
                                   16, 0, 0);
}

__device__ __forceinline__ uint32_t pack_f16x2(f16 lo, f16 hi) {
  union { f16 h[2]; uint32_t u; } c;
  c.h[0] = lo; c.h[1] = hi;
  return c.u;
}

// ---------------- elementwise helpers ----------------

__global__ void cvt_f16_kernel(const float* __restrict__ src, f16* __restrict__ dst, int n4) {
  int i = blockIdx.x * blockDim.x + threadIdx.x;
  const int stride = gridDim.x * blockDim.x;
  for (; i < n4; i += stride) {
    float4 v = reinterpret_cast<const float4*>(src)[i];
    f16x4 o = { (f16)v.x, (f16)v.y, (f16)v.z, (f16)v.w };
    reinterpret_cast<f16x4*>(dst)[i] = o;
  }
}

__global__ void gather_x_kernel(const int* __restrict__ seq, const float* __restrict__ emb,
                                f16* __restrict__ xh) {
  const int m = blockIdx.x;               // 0..2047 = n*64+b
  const int tok = seq[m];
  float4 v = reinterpret_cast<const float4*>(emb + (size_t)tok * kH)[threadIdx.x];
  f16x4 o = { (f16)v.x, (f16)v.y, (f16)v.z, (f16)v.w };
  reinterpret_cast<f16x4*>(xh + (size_t)m * kH)[threadIdx.x] = o;
}

__global__ void init_h_kernel(const float* __restrict__ lh, f16* __restrict__ hh0) {
  const int i = blockIdx.x * blockDim.x + threadIdx.x;   // 16384 float4s
  float4 v = reinterpret_cast<const float4*>(lh)[i];
  f16x4 o = { (f16)v.x, (f16)v.y, (f16)v.z, (f16)v.w };
  reinterpret_cast<f16x4*>(hh0)[i] = o;
}

__global__ void attn_prep_kernel(const float* __restrict__ attn_W, const float* __restrict__ attn_b,
                                 const float* __restrict__ v, float* __restrict__ u2,
                                 float* __restrict__ biasS) {
  const int h = blockIdx.x;        // 0..1023 -> u2[h]; 1024 -> bias scalar
  const int lane = threadIdx.x;    // 64
  float sum = 0.0f;
  if (h < kH) {
    for (int k = lane; k < kH; k += 64)
      sum += attn_W[(size_t)k * (2 * kH) + kH + h] * v[k];
  } else {
    for (int k = lane; k < kH; k += 64)
      sum += attn_b[k] * v[k];
  }
  #pragma unroll
  for (int o = 32; o > 0; o >>= 1) sum += __shfl_xor(sum, o);
  if (lane == 0) {
    if (h < kH) u2[h] = sum; else biasS[0] = sum;
  }
}

// ---------------- main GEMM: C = A * Bt^T (+bias)(+tanh)(NT stores) ----------------

template <bool TANH, bool NT, typename OUT_T>
__global__ __launch_bounds__(256)
void gemm_bt_kernel(const f16* __restrict__ A, const f16* __restrict__ Bt,
                    const float* __restrict__ bias, OUT_T* __restrict__ C,
                    int M, int N, int K) {
  __shared__ __align__(16) f16 As[128 * 64];
  __shared__ __align__(16) f16 Bs[128 * 64];
  const int tid  = threadIdx.x;
  const int wave = tid >> 6;
  const int lane = tid & 63;
  const int m0 = blockIdx.x * 128;
  const int n0 = blockIdx.y * 128;
  const int wm = (wave >> 1) * 64;
  const int wn = (wave & 1) * 64;
  const int rsub = lane >> 3;
  const int coff = (lane & 7) * 8;
  f32x4v acc[4][4] = {};
  const int nk = K >> 6;
  for (int kc = 0; kc < nk; ++kc) {
    const f16* Ag = A + (size_t)m0 * K + kc * 64;
    const f16* Bg = Bt + (size_t)n0 * K + kc * 64;
    for (int c = wave; c < 16; c += 4) {
      const int row = c * 8 + rsub;
      gload_lds16(Ag + (size_t)row * K + coff, &As[c * 512]);
      gload_lds16(Bg + (size_t)row * K + coff, &Bs[c * 512]);
    }
    __syncthreads();
    #pragma unroll
    for (int kk = 0; kk < 2; ++kk) {
      const int ko = kk * 32 + (lane >> 4) * 8;
      f16x8 af[4], bfr[4];
      #pragma unroll
      for (int i = 0; i < 4; ++i) {
        af[i]  = *reinterpret_cast<const f16x8*>(&As[(wm + i * 16 + (lane & 15)) * 64 + ko]);
        bfr[i] = *reinterpret_cast<const f16x8*>(&Bs[(wn + i * 16 + (lane & 15)) * 64 + ko]);
      }
      #pragma unroll
      for (int mi = 0; mi < 4; ++mi)
        #pragma unroll
        for (int ni = 0; ni < 4; ++ni)
          acc[mi][ni] = __builtin_amdgcn_mfma_f32_16x16x32_f16(af[mi], bfr[ni], acc[mi][ni], 0, 0, 0);
    }
    __syncthreads();
  }
  const int rb = (lane >> 4) * 4;
  const int cb = lane & 15;
  #pragma unroll
  for (int mi = 0; mi < 4; ++mi) {
    #pragma unroll
    for (int ni = 0; ni < 4; ++ni) {
      const int col = n0 + wn + ni * 16 + cb;
      const float bv = bias[col];
      #pragma unroll
      for (int r = 0; r < 4; ++r) {
        const int row = m0 + wm + mi * 16 + rb + r;
        float v = acc[mi][ni][r] + bv;
        if (TANH) v = tanhf(v);
        if (NT) __builtin_nontemporal_store((OUT_T)v, &C[(size_t)row * N + col]);
        else C[(size_t)row * N + col] = (OUT_T)v;
      }
    }
  }
}

// ---------------- MEGA kernel: gru (0..63) | attn (64..191) | cvt (192..511) ----------------
// gru: persistent, block owns 16 output cols; W_hh slices in registers; own-col
//   h in f32 regs (1 row x 4 cols per thread); exchange via single 8B sc1 store
//   per thread; flag publish/poll at SYSTEM scope (sc0+sc1 -> fresh L3 reads,
//   no per-poll invalidate); one agent acquire fence per wave per step.
// attn: self-contained per (e,b): scores -> softmax -> replicated uw/bw -> ctx.
// cvt: grid-stride f32->f16 of out_W and concat_W (independent of gru).

constexpr int kGruBlks = 64;
constexpr int kAttnBlks = 128;
constexpr int kCvtBlks = 320;
constexpr int kMegaBlks = kGruBlks + kAttnBlks + kCvtBlks;

__global__ __launch_bounds__(256, 1)
void mega_kernel(const f16* __restrict__ Whh, const float* __restrict__ bhh,
                 const float* __restrict__ gi, const float* __restrict__ lh,
                 f16* __restrict__ HHa, f16* __restrict__ HHb,
                 f16* __restrict__ cath, float* __restrict__ hiddenOut,
                 unsigned int* __restrict__ flags,
                 const float* __restrict__ enc0, const float* __restrict__ enc1,
                 const float* __restrict__ u2, const float* __restrict__ biasS,
                 float* __restrict__ uw, float* __restrict__ bw,
                 const float* __restrict__ oW, f16* __restrict__ oWh,
                 const float* __restrict__ cW, f16* __restrict__ cWh) {
  __shared__ union SM {
    float ghp[4][64][52];                       // gru: [wave][m][48 cols pad52]
    struct { float4 u2s[256]; float srow[kT]; float red[8]; } at;
  } sm;
  const int bid = blockIdx.x;
  const int tid = threadIdx.x;

  if (bid < kGruBlks) {
    // ================= GRU role =================
    const int wave = tid >> 6;
    const int lane = tid & 63;
    const int ln   = lane & 15;
    const int khi  = lane >> 4;
    const int j0   = bid * 16;
    const int kw   = wave * 256;
    const int fm   = tid >> 2;          // fusion row 0..63
    const int fc   = (tid & 3) * 4;     // fusion col group (4 cols)
    const int myprod = wave * 16 + ln;

    f16x8 bfr[3][8];
    #pragma unroll
    for (int s = 0; s < 3; ++s)
      #pragma unroll
      for (int ks = 0; ks < 8; ++ks)
        bfr[s][ks] = *reinterpret_cast<const f16x8*>(
            &Whh[(size_t)(s * kH + j0 + ln) * kH + kw + ks * 32 + khi * 8]);

    float hreg[4], bR[4], bZ[4], bN[4];
    #pragma unroll
    for (int e = 0; e < 4; ++e) {
      const int j = j0 + fc + e;
      hreg[e] = lh[(size_t)fm * kH + j];
      bR[e] = bhh[j]; bZ[e] = bhh[kH + j]; bN[e] = bhh[2 * kH + j];
    }

    for (int step = 0; step < kN; ++step) {
      const f16* hh  = (step & 1) ? HHb : HHa;
      f16*       hho = (step & 1) ? HHa : HHb;

      // gi prefetch (no h dependence; flies during poll)
      float4 giL[3];
      {
        const size_t mm = (size_t)step * kB + fm;
        #pragma unroll
        for (int s = 0; s < 3; ++s)
          giL[s] = *reinterpret_cast<const float4*>(&gi[mm * k3H + s * kH + j0 + fc]);
      }

      if (step > 0) {
        while (true) {
          unsigned int f = __hip_atomic_load(&flags[myprod], __ATOMIC_RELAXED,
                                             __HIP_MEMORY_SCOPE_SYSTEM);
          if (__all(f >= (unsigned int)step)) break;
          __builtin_amdgcn_s_sleep(1);
        }
        __builtin_amdgcn_fence(__ATOMIC_ACQUIRE, "agent");  // inv stale h lines
      }

      f16x8 af[8][4];
      #pragma unroll
      for (int ks = 0; ks < 8; ++ks)
        #pragma unroll
        for (int mi = 0; mi < 4; ++mi)
          af[ks][mi] = *reinterpret_cast<const f16x8*>(
              &hh[(size_t)(mi * 16 + ln) * kH + kw + ks * 32 + khi * 8]);

      f32x4v acc[4][3] = {};
      #pragma unroll
      for (int ks = 0; ks < 8; ++ks)
        #pragma unroll
        for (int mi = 0; mi < 4; ++mi)
          #pragma unroll
          for (int s = 0; s < 3; ++s)
            acc[mi][s] = __builtin_amdgcn_mfma_f32_16x16x32_f16(af[ks][mi], bfr[s][ks], acc[mi][s], 0, 0, 0);

      #pragma unroll
      for (int mi = 0; mi < 4; ++mi)
        #pragma unroll
        for (int s = 0; s < 3; ++s)
          #pragma unroll
          for (int r = 0; r < 4; ++r)
            sm.ghp[wave][mi * 16 + khi * 4 + r][s * 16 + ln] = acc[mi][s][r];
      __syncthreads();

      // fusion: 1 row (fm) x 4 cols (fc..fc+3) per thread
      float4 gr4 = {0,0,0,0}, gz4 = {0,0,0,0}, gn4 = {0,0,0,0};
      #pragma unroll
      for (int w = 0; w < 4; ++w) {
        float4 a = *reinterpret_cast<const float4*>(&sm.ghp[w][fm][fc]);
        float4 b = *reinterpret_cast<const float4*>(&sm.ghp[w][fm][16 + fc]);
        float4 c = *reinterpret_cast<const float4*>(&sm.ghp[w][fm][32 + fc]);
        gr4.x += a.x; gr4.y += a.y; gr4.z += a.z; gr4.w += a.w;
        gz4.x += b.x; gz4.y += b.y; gz4.z += b.z; gz4.w += b.w;
        gn4.x += c.x; gn4.y += c.y; gn4.z += c.z; gn4.w += c.w;
      }
      float hv[4];
      const float* grp = &gr4.x; const float* gzp = &gz4.x; const float* gnp = &gn4.x;
      const float* gil0 = &giL[0].x; const float* gil1 = &giL[1].x; const float* gil2 = &giL[2].x;
      #pragma unroll
      for (int e = 0; e < 4; ++e) {
        const float r  = 1.0f / (1.0f + expf(-(gil0[e] + grp[e] + bR[e])));
        const float z  = 1.0f / (1.0f + expf(-(gil1[e] + gzp[e] + bZ[e])));
        const float nn = tanhf(gil2[e] + r * (gnp[e] + bN[e]));
        hv[e] = (1.0f - z) * nn + z * hreg[e];
        hreg[e] = hv[e];
      }
      const uint32_t p01 = pack_f16x2((f16)hv[0], (f16)hv[1]);
      const uint32_t p23 = pack_f16x2((f16)hv[2], (f16)hv[3]);
      const unsigned long long pk64 = (unsigned long long)p01 | ((unsigned long long)p23 << 32);
      // single 8B sc1 store on the drain path
      __hip_atomic_store(reinterpret_cast<unsigned long long*>(&hho[(size_t)fm * kH + j0 + fc]),
                         pk64, __ATOMIC_RELAXED, __HIP_MEMORY_SCOPE_AGENT);
      __syncthreads();   // drains vmcnt -> hho at coherence point; guards ghp
      if (step < kN - 1 && tid == 0)
        __hip_atomic_store(&flags[bid], (unsigned int)(step + 1),
                           __ATOMIC_RELAXED, __HIP_MEMORY_SCOPE_SYSTEM);
      // non-gating stores after flag publish (overlap next step)
      uint2 pku; pku.x = p01; pku.y = p23;
      *reinterpret_cast<uint2*>(&cath[((size_t)step * kB + fm) * k3H + j0 + fc]) = pku;
      if (step == kN - 1) {
        float4 hv4 = { hv[0], hv[1], hv[2], hv[3] };
        *reinterpret_cast<float4*>(&hiddenOut[(size_t)fm * kH + j0 + fc]) = hv4;
      }
    }
  } else if (bid < kGruBlks + kAttnBlks) {
    // ================= attention role =================
    const int idx = bid - kGruBlks;
    const int e = idx >> 6, b = idx & 63;
    const float* enc = e ? enc1 : enc0;
    const int wave = tid >> 6, lane = tid & 63;

    sm.at.u2s[tid] = *reinterpret_cast<const float4*>(&u2[tid * 4]);
    __syncthreads();
    const float bias = biasS[0];

    for (int t = wave; t < kT; t += 4) {
      const float* row = enc + ((size_t)t * kB + b) * kH + lane * 16;
      float s = 0.0f;
      #pragma unroll
      for (int i = 0; i < 4; ++i) {
        float4 ev = reinterpret_cast<const float4*>(row)[i];
        float4 uv = sm.at.u2s[lane * 4 + i];
        s += ev.x * uv.x + ev.y * uv.y + ev.z * uv.z + ev.w * uv.w;
      }
      #pragma unroll
      for (int o = 32; o > 0; o >>= 1) s += __shfl_xor(s, o);
      if (lane == 0) sm.at.srow[t] = s + bias;
    }
    __syncthreads();

    float lmax = -1e30f;
    for (int t = tid; t < kT; t += 256) lmax = fmaxf(lmax, sm.at.srow[t]);
    #pragma unroll
    for (int o = 32; o > 0; o >>= 1) lmax = fmaxf(lmax, __shfl_xor(lmax, o));
    if (lane == 0) sm.at.red[wave] = lmax;
    __syncthreads();
    const float m = fmaxf(fmaxf(sm.at.red[0], sm.at.red[1]), fmaxf(sm.at.red[2], sm.at.red[3]));
    float lsum = 0.0f;
    for (int t = tid; t < kT; t += 256) {
      float ev = expf(sm.at.srow[t] - m);
      sm.at.srow[t] = ev;
      lsum += ev;
    }
    #pragma unroll
    for (int o = 32; o > 0; o >>= 1) lsum += __shfl_xor(lsum, o);
    if (lane == 0) sm.at.red[4 + wave] = lsum;
    __syncthreads();
    const float inv = 1.0f / (sm.at.red[4] + sm.at.red[5] + sm.at.red[6] + sm.at.red[7]);
    for (int t = tid; t < kT; t += 256) sm.at.srow[t] *= inv;
    __syncthreads();

    // replicated uw/bw (never re-read on device -> nt)
    float* outp = (e ? bw : uw) + (size_t)b * kN * kT;
    for (int n = 0; n < kN; ++n)
      for (int t = tid; t < kT; t += 256)
        __builtin_nontemporal_store(sm.at.srow[t], &outp[n * kT + t]);

    // ctx: col group of 4 per thread, accumulate over t
    const int j = tid * 4;
    float4 acc = {0,0,0,0};
    for (int t = 0; t < kT; ++t) {
      const float wt = sm.at.srow[t];
      const float4 ev = *reinterpret_cast<const float4*>(&enc[((size_t)t * kB + b) * kH + j]);
      acc.x += wt * ev.x; acc.y += wt * ev.y; acc.z += wt * ev.z; acc.w += wt * ev.w;
    }
    f16x4 cv = { (f16)acc.x, (f16)acc.y, (f16)acc.z, (f16)acc.w };
    #pragma unroll
    for (int n = 0; n < kN; ++n)
      *reinterpret_cast<f16x4*>(&cath[((size_t)(n * kB + b)) * k3H + kH + e * kH + j]) = cv;
  } else {
    // ================= cvt role: oW then cW =================
    constexpr int nOW = kV * kH / 4;
    constexpr int nCW = kH * k3H / 4;
    const int stride = kCvtBlks * 256;
    for (int i = (bid - kGruBlks - kAttnBlks) * 256 + tid; i < nOW + nCW; i += stride) {
      if (i < nOW) {
        float4 v = reinterpret_cast<const float4*>(oW)[i];
        f16x4 o = { (f16)v.x, (f16)v.y, (f16)v.z, (f16)v.w };
        reinterpret_cast<f16x4*>(oWh)[i] = o;
      } else {
        const int k = i - nOW;
        float4 v = reinterpret_cast<const float4*>(cW)[k];
        f16x4 o = { (f16)v.x, (f16)v.y, (f16)v.z, (f16)v.w };
        reinterpret_cast<f16x4*>(cWh)[k] = o;
      }
    }
  }
}

}  // namespace

// ---------------- launch ----------------

extern "C" void kernel_launch(void* const* d_in, const int* in_sizes, int n_in,
                              void* d_out, int out_size, void* d_ws, size_t ws_size,
                              hipStream_t stream) {
  (void)in_sizes; (void)n_in; (void)out_size; (void)ws_size;
  const int*   seq    = (const int*)d_in[0];
  const float* lh     = (const float*)d_in[1];
  const float* enc0   = (const float*)d_in[2];
  const float* enc1   = (const float*)d_in[3];
  const float* emb    = (const float*)d_in[4];
  const float* W_ih   = (const float*)d_in[5];
  const float* W_hh   = (const float*)d_in[6];
  const float* b_ih   = (const float*)d_in[7];
  const float* b_hh   = (const float*)d_in[8];
  const float* attn_W = (const float*)d_in[9];
  const float* attn_b = (const float*)d_in[10];
  const float* attn_v = (const float*)d_in[11];
  const float* cW     = (const float*)d_in[12];
  const float* cb     = (const float*)d_in[13];
  const float* oW     = (const float*)d_in[14];
  const float* ob     = (const float*)d_in[15];
  float* out = (float*)d_out;

  char* ws = (char*)d_ws;
  constexpr size_t oWih = 0;                         // 3072x1024 f16
  constexpr size_t oWhh = oWih + 6291456;
  constexpr size_t oCW  = oWhh + 6291456;
  constexpr size_t oOW  = oCW + 6291456;             // 32000x1024 f16
  constexpr size_t oX   = oOW + 65536000;            // 2048x1024 f16
  constexpr size_t oGI  = oX + 4194304;              // 2048x3072 f32
  constexpr size_t oH0  = oGI + 25165824;            // (spare)
  constexpr size_t oH1  = oH0 + 262144;
  constexpr size_t oHH0 = oH1 + 262144;              // 64x1024 f16
  constexpr size_t oHH1 = oHH0 + 131072;
  constexpr size_t oCAT = oHH1 + 131072;             // 2048x3072 f16
  constexpr size_t oH2  = oCAT + 12582912;           // 2048x1024 f16
  constexpr size_t oU2  = oH2 + 4194304;             // 1024 f32
  constexpr size_t oBS  = oU2 + 4096;                // 1 f32
  constexpr size_t oC   = oBS + 256;                 // spare
  constexpr size_t oWSM = oC + 204800;               // spare
  constexpr size_t oCTR = oWSM + 204800;             // 64 u32 epoch flags

  f16*   Wih_h = (f16*)(ws + oWih);
  f16*   Whh_h = (f16*)(ws + oWhh);
  f16*   cW_h  = (f16*)(ws + oCW);
  f16*   oW_h  = (f16*)(ws + oOW);
  f16*   X_h   = (f16*)(ws + oX);
  float* GI    = (float*)(ws + oGI);
  f16*   HH0   = (f16*)(ws + oHH0);
  f16*   HH1   = (f16*)(ws + oHH1);
  f16*   CAT   = (f16*)(ws + oCAT);
  f16*   H2    = (f16*)(ws + oH2);
  float* U2    = (float*)(ws + oU2);
  float* BS    = (float*)(ws + oBS);
  unsigned int* FLAGS = (unsigned int*)(ws + oCTR);

  constexpr size_t oHidden = (size_t)kM * kV;        // 65,536,000
  constexpr size_t oUW = oHidden + (size_t)kB * kH;  // 65,601,536
  constexpr size_t oBW = oUW + (size_t)kB * kN * kT; // 66,420,736

  // upfront: converts needed before gi GEMM / mega, gather, init, u2 prep
  cvt_f16_kernel<<<1024, 256, 0, stream>>>(W_ih, Wih_h, k3H * kH / 4);
  cvt_f16_kernel<<<1024, 256, 0, stream>>>(W_hh, Whh_h, k3H * kH / 4);
  gather_x_kernel<<<kM, 256, 0, stream>>>(seq, emb, X_h);
  init_h_kernel<<<64, 256, 0, stream>>>(lh, HH0);
  attn_prep_kernel<<<1025, 64, 0, stream>>>(attn_W, attn_b, attn_v, U2, BS);
  hipMemsetAsync(FLAGS, 0, 64 * sizeof(unsigned int), stream);

  // gi = x @ W_ih^T + b_ih
  gemm_bt_kernel<false, false, float><<<dim3(16, 24), 256, 0, stream>>>(X_h, Wih_h, b_ih, GI, kM, k3H, kH);

  // MEGA: gru recurrence || attention || oW/cW converts
  mega_kernel<<<kMegaBlks, 256, 0, stream>>>(Whh_h, b_hh, GI, lh, HH0, HH1, CAT,
                                             out + oHidden, FLAGS,
                                             enc0, enc1, U2, BS,
                                             out + oUW, out + oBW,
                                             oW, oW_h, cW, cW_h);

  // h = tanh(cat @ concat_W^T + concat_b)
  gemm_bt_kernel<true, false, f16><<<dim3(16, 8), 256, 0, stream>>>(CAT, cW_h, cb, H2, kM, kH, k3H);
  // output = h @ out_W^T + out_b   (nontemporal C: avoid write-allocate fetch)
  gemm_bt_kernel<false, true, float><<<dim3(16, 250), 256, 0, stream>>>(H2, oW_h, ob, out, kM, kV, kH);
}